// Round 13
// baseline (1873.893 us; speedup 1.0000x reference)
//
#include <hip/hip_runtime.h>
#include <hip/hip_cooperative_groups.h>

namespace cg = cooperative_groups;

#define NN 131072          // nodes (2^17)
#define NE 4194304         // edges
#define HID 8
#define BSZ 16
#define MDIM 1000
#define ODIM 34
#define FC 128             // f-chunk per lin1 block
#define NCHUNK 512         // 65536 / FC
#define NB 1024            // edge stripes for binning
#define EPB (NE / NB)      // 4096
#define NBUK 1024          // dst buckets (128 nodes each)
#define CNOD 128
#define NBUKR 512          // row buckets (256 nodes each)
#define SCAP 6144          // bucket sort LDS capacity
#define MGRID 512          // mega-kernel blocks (2 buckets each)

typedef float f4v __attribute__((ext_vector_type(4)));
typedef _Float16 h8v __attribute__((ext_vector_type(8)));

// ---------------- binning build (no global atomics) ----------------
__global__ __launch_bounds__(512) void bin_count(const int* __restrict__ ei,
                                                 int* __restrict__ colhist,
                                                 int* __restrict__ rowhist) {
    __shared__ int ch[NBUK];
    __shared__ int rh[NBUKR];
    int b = blockIdx.x, t = threadIdx.x;
    for (int i = t; i < NBUK; i += 512) ch[i] = 0;
    for (int i = t; i < NBUKR; i += 512) rh[i] = 0;
    __syncthreads();
    int base = b * EPB;
    for (int k = t; k < EPB; k += 512) {
        int e = base + k;
        int r = __builtin_nontemporal_load(&ei[e]);
        int c = __builtin_nontemporal_load(&ei[NE + e]);
        if (r != c) { atomicAdd(&ch[c >> 7], 1); atomicAdd(&rh[r >> 8], 1); }
    }
    __syncthreads();
    for (int i = t; i < NBUK; i += 512) colhist[b * NBUK + i] = ch[i];
    for (int i = t; i < NBUKR; i += 512) rowhist[b * NBUKR + i] = rh[i];
}

__global__ __launch_bounds__(NB) void bin_scan(int* __restrict__ hist,
                                               int* __restrict__ tot, int nbuckets) {
    __shared__ int s[NB];
    int i = blockIdx.x, t = threadIdx.x;
    int v = hist[(size_t)t * nbuckets + i];
    s[t] = v; __syncthreads();
    for (int off = 1; off < NB; off <<= 1) {
        int x = (t >= off) ? s[t - off] : 0;
        __syncthreads(); s[t] += x; __syncthreads();
    }
    hist[(size_t)t * nbuckets + i] = s[t] - v;
    if (t == NB - 1) tot[i] = s[t];
}

template <int M>
__global__ __launch_bounds__(256) void base_scan(const int* __restrict__ tot,
                                                 int* __restrict__ basev) {
    __shared__ int s[256];
    int t = threadIdx.x;
    int v[M]; int ps = 0;
    #pragma unroll
    for (int q = 0; q < M; ++q) { v[q] = tot[t * M + q]; ps += v[q]; }
    s[t] = ps; __syncthreads();
    for (int off = 1; off < 256; off <<= 1) {
        int x = (t >= off) ? s[t - off] : 0;
        __syncthreads(); s[t] += x; __syncthreads();
    }
    int run = s[t] - ps;
    #pragma unroll
    for (int q = 0; q < M; ++q) { basev[t * M + q] = run; run += v[q]; }
}

__global__ __launch_bounds__(512) void bin_fill(const int* __restrict__ ei,
                                                const int* __restrict__ colhist,
                                                const int* __restrict__ rowhist,
                                                const int* __restrict__ colbase,
                                                const int* __restrict__ rowbase,
                                                unsigned int* __restrict__ colbinned,
                                                unsigned char* __restrict__ rowbinned) {
    __shared__ int cc[NBUK];
    __shared__ int rc[NBUKR];
    int b = blockIdx.x, t = threadIdx.x;
    for (int i = t; i < NBUK; i += 512) cc[i] = colbase[i] + colhist[b * NBUK + i];
    for (int i = t; i < NBUKR; i += 512) rc[i] = rowbase[i] + rowhist[b * NBUKR + i];
    __syncthreads();
    int base = b * EPB;
    for (int k = t; k < EPB; k += 512) {
        int e = base + k;
        int r = __builtin_nontemporal_load(&ei[e]);
        int c = __builtin_nontemporal_load(&ei[NE + e]);
        if (r != c) {
            int p = atomicAdd(&cc[c >> 7], 1);
            colbinned[p] = ((unsigned)r << 7) | (unsigned)(c & 127);
            int q = atomicAdd(&rc[r >> 8], 1);
            rowbinned[q] = (unsigned char)(r & 255);
        }
    }
}

// per-bucket counting sort by dst node (cl) + per-node CSR offsets o[] (absolute).
__global__ __launch_bounds__(256) void bucket_sort2(unsigned int* __restrict__ colbinned,
                                                    const int* __restrict__ colbase,
                                                    const int* __restrict__ coltot,
                                                    int* __restrict__ o,
                                                    int* __restrict__ sflag) {
    __shared__ unsigned int recs[SCAP];
    __shared__ int cnt[CNOD], scn[CNOD], cur[CNOD];
    int b = blockIdx.x, t = threadIdx.x;
    int s0 = colbase[b], n = coltot[b];
    if (n > SCAP) {
        if (t == 0) sflag[b] = 1;
        for (int i = t; i < CNOD; i += 256) o[b * CNOD + i] = s0;
        if (b == NBUK - 1 && t == 0) o[NN] = s0 + n;
        return;
    }
    if (t == 0) sflag[b] = 0;
    for (int i = t; i < CNOD; i += 256) cnt[i] = 0;
    __syncthreads();
    for (int i = t; i < n; i += 256) {
        unsigned int rec = colbinned[s0 + i];
        recs[i] = rec;
        atomicAdd(&cnt[rec & 127], 1);
    }
    __syncthreads();
    if (t < CNOD) scn[t] = cnt[t];
    __syncthreads();
    for (int off = 1; off < CNOD; off <<= 1) {
        int v = 0;
        if (t < CNOD && t >= off) v = scn[t - off];
        __syncthreads();
        if (t < CNOD) scn[t] += v;
        __syncthreads();
    }
    if (t < CNOD) {
        int ex = scn[t] - cnt[t];
        cur[t] = ex;
        o[b * CNOD + t] = s0 + ex;
    }
    __syncthreads();
    if (b == NBUK - 1 && t == 0) o[NN] = s0 + n;
    for (int i = t; i < n; i += 256) {
        unsigned int rec = recs[i];
        int p = atomicAdd(&cur[rec & 127], 1);
        colbinned[s0 + p] = rec;
    }
}

__global__ __launch_bounds__(256) void deg_finish(const unsigned char* __restrict__ rowbinned,
                                                  const int* __restrict__ rowbase,
                                                  const int* __restrict__ rowtot,
                                                  const float* __restrict__ x,
                                                  float* __restrict__ dinv,
                                                  float* __restrict__ rinv,
                                                  float* __restrict__ sx) {
    __shared__ int cnt[256];
    int b = blockIdx.x, t = threadIdx.x;
    cnt[t] = 0; __syncthreads();
    int s0 = rowbase[b], n = rowtot[b];
    for (int i = t; i < n; i += 256) atomicAdd(&cnt[rowbinned[s0 + i]], 1);
    __syncthreads();
    int d = cnt[t];
    int node = b * 256 + t;
    float dn = (d > 0) ? rsqrtf((float)d) : 0.f;
    dinv[node] = dn;
    rinv[node] = (d > 0) ? sqrtf((float)d) : 1.f;
    sx[node] = ((d > 0) ? dn : 1.f) * x[node];
}

// ================= cooperative mega-kernel (small LDS, global sorted runs) =================
struct MegaP {
    const unsigned int* colbinned;
    const int* colbase; const int* coltot; const int* o; const int* sflag;
    const float* dinv; const float* rinv;
    const float* x; const float* sx;
    float* wt1; float* wt2; float* wt3; float* wt4;
    const float* W1; const float* b1; const float* W2; const float* b2;
    float* sh1; _Float16* s1t; _Float16* s2t;
    float* wA; float* wB; float* accg;
};

__global__ __launch_bounds__(512, 4) void cheb_mega(MegaP p) {
    cg::grid_group grid = cg::this_grid();
    __shared__ float vb[CNOD][HID];     // 4 KB
    __shared__ float wkL[64];
    __shared__ float accF[CNOD * 9];    // 4.6 KB (fallback scratch)
    int blk = blockIdx.x, t = threadIdx.x;
    int nl = t >> 2, l = t & 3;

    // ---- layer 1: 4 scalar cheb passes (scaled w-space, fp32) ----
    const float* w1in[4]  = { p.sx, p.wt1, p.wt2, p.wt3 };
    const float* w1p2[4]  = { nullptr, p.sx, p.wt1, p.wt2 };
    float*       w1out[4] = { p.wt1, p.wt2, p.wt3, p.wt4 };
    #pragma unroll
    for (int ps = 0; ps < 4; ++ps) {
        const float* win = w1in[ps];
        const float* wp2 = w1p2[ps];
        float* wout = w1out[ps];
        for (int bk = 0; bk < 2; ++bk) {
            int b = blk * 2 + bk;
            int nb = b * CNOD;
            int node = nb + nl;
            float a = 0.f;
            if (!p.sflag[b]) {
                int i0 = p.o[node], i1 = p.o[node + 1];
                for (int i = i0 + l; i < i1; i += 4)
                    a += win[__builtin_nontemporal_load(&p.colbinned[i]) >> 7];
            } else {                      // rare fallback: LDS atomics over raw bucket
                for (int i = t; i < CNOD; i += 512) accF[i] = 0.f;
                __syncthreads();
                int s0 = p.colbase[b], n = p.coltot[b];
                for (int i = t; i < n; i += 512) {
                    unsigned int rec = p.colbinned[s0 + i];
                    atomicAdd(&accF[rec & 127], win[rec >> 7]);
                }
                __syncthreads();
                if (l == 0) a = accF[nl];
                __syncthreads();
            }
            a += __shfl_xor(a, 1);
            a += __shfl_xor(a, 2);
            if (l == 0) {
                float dn = p.dinv[node];
                float lh = (dn > 0.f) ? -dn * a : -win[node];
                float s = (dn > 0.f) ? dn : 1.f;
                wout[node] = (ps == 0) ? s * lh : s * (2.f * lh) - wp2[node];
            }
        }
        __threadfence();
        grid.sync();
    }

    // ---- h1: per-node MLP; writes sh1 (fp32), s1t (fp16), accg = b2 + h1@W2[0] ----
    if (t < 256) {
        int n = blk * 256 + t;
        float rn = p.rinv[n], dn = p.dinv[n];
        float s = (dn > 0.f) ? dn : 1.f;
        float T0 = p.x[n], T1 = p.wt1[n] * rn, T2 = p.wt2[n] * rn,
              T3 = p.wt3[n] * rn, T4 = p.wt4[n] * rn;
        float h[HID];
        #pragma unroll
        for (int j = 0; j < HID; ++j) {
            float v = p.b1[j] + T0 * p.W1[j] + T1 * p.W1[8 + j] + T2 * p.W1[16 + j]
                    + T3 * p.W1[24 + j] + T4 * p.W1[32 + j];
            h[j] = fmaxf(v, 0.f);
        }
        f4v sv0, sv1, av0, av1;
        h8v hv;
        #pragma unroll
        for (int j = 0; j < 4; ++j) { sv0[j] = s * h[j]; sv1[j] = s * h[4 + j]; }
        #pragma unroll
        for (int j = 0; j < 8; ++j) hv[j] = (_Float16)(s * h[j]);
        #pragma unroll
        for (int o2 = 0; o2 < HID; ++o2) {
            float v = p.b2[o2];
            #pragma unroll
            for (int j = 0; j < HID; ++j) v = fmaf(h[j], p.W2[j * 8 + o2], v);
            if (o2 < 4) av0[o2] = v; else av1[o2 - 4] = v;
        }
        *(f4v*)&p.sh1[n * 8] = sv0;  *(f4v*)&p.sh1[n * 8 + 4] = sv1;
        *(h8v*)&p.s1t[n * 8] = hv;
        *(f4v*)&p.accg[n * 8] = av0; *(f4v*)&p.accg[n * 8 + 4] = av1;
    }
    __threadfence();
    grid.sync();

    // ---- layer 2: 4 cheb passes (fp16 gather tables, fused W2[k]) ----
    const _Float16* w2in16[4]  = { p.s1t, p.s2t, p.s1t, p.s2t };
    const float*    w2in[4]    = { p.sh1, p.wA, p.wB, p.wA };
    const float*    w2p2[4]    = { nullptr, p.sh1, p.wA, p.wB };
    float*          w2out[4]   = { p.wA, p.wB, p.wA, nullptr };
    _Float16*       w2out16[4] = { p.s2t, p.s1t, p.s2t, nullptr };
    #pragma unroll
    for (int ps = 0; ps < 4; ++ps) {
        const _Float16* win16 = w2in16[ps];
        const float* wfp = w2in[ps];
        const float* wp2 = w2p2[ps];
        float* wo = w2out[ps];
        _Float16* wo16 = w2out16[ps];
        if (t < 64) wkL[t] = p.W2[64 * (ps + 1) + t];
        for (int bk = 0; bk < 2; ++bk) {
            int b = blk * 2 + bk;
            int nb = b * CNOD;
            int node = nb + nl;
            float a[8];
            #pragma unroll
            for (int j = 0; j < 8; ++j) a[j] = 0.f;
            if (!p.sflag[b]) {
                int i0 = p.o[node], i1 = p.o[node + 1];
                for (int i = i0 + l; i < i1; i += 4) {
                    unsigned int rec = __builtin_nontemporal_load(&p.colbinned[i]);
                    h8v v = *(const h8v*)&win16[(rec >> 7) * 8];
                    #pragma unroll
                    for (int j = 0; j < 8; ++j) a[j] += (float)v[j];
                }
            } else {                      // rare fallback
                for (int i = t; i < CNOD * 9; i += 512) accF[i] = 0.f;
                __syncthreads();
                int s0 = p.colbase[b], n = p.coltot[b];
                for (int i = t; i < n; i += 512) {
                    unsigned int rec = p.colbinned[s0 + i];
                    h8v v = *(const h8v*)&win16[(rec >> 7) * 8];
                    float* ap = &accF[(rec & 127) * 9];
                    #pragma unroll
                    for (int j = 0; j < 8; ++j) atomicAdd(ap + j, (float)v[j]);
                }
                __syncthreads();
                if (l == 0) {
                    #pragma unroll
                    for (int j = 0; j < 8; ++j) a[j] = accF[nl * 9 + j];
                }
                __syncthreads();
            }
            #pragma unroll
            for (int j = 0; j < 8; ++j) {
                a[j] += __shfl_xor(a[j], 1);
                a[j] += __shfl_xor(a[j], 2);
            }
            if (l == 0) {
                float dn = p.dinv[node];
                float rn = p.rinv[node];
                #pragma unroll
                for (int j = 0; j < 8; ++j) {
                    float lh = (dn > 0.f) ? -dn * a[j] : -wfp[node * 8 + j];
                    float T;
                    if (ps == 0) {
                        T = lh;
                        float w = (dn > 0.f) ? dn * lh : lh;
                        wo[node * 8 + j] = w;
                        wo16[node * 8 + j] = (_Float16)w;
                    } else if (ps < 3) {
                        float sc = (dn > 0.f) ? dn : 1.f;
                        float w = sc * (2.f * lh) - wp2[node * 8 + j];
                        wo[node * 8 + j] = w;
                        wo16[node * 8 + j] = (_Float16)w;
                        T = w * rn;
                    } else {
                        T = 2.f * lh - wp2[node * 8 + j] * rn;
                    }
                    vb[nl][j] = T;
                }
            }
            __syncthreads();
            // fused accg += T @ W2[ps+1] (relu at final pass)
            #pragma unroll
            for (int k2 = 0; k2 < 2; ++k2) {
                int idx = k2 * 512 + t;
                int n2 = idx >> 3, jj = idx & 7;
                int nd = nb + n2;
                float sum = 0.f;
                #pragma unroll
                for (int q = 0; q < HID; ++q) sum = fmaf(vb[n2][q], wkL[q * 8 + jj], sum);
                float r2 = p.accg[nd * 8 + jj] + sum;
                p.accg[nd * 8 + jj] = (ps == 3) ? fmaxf(r2, 0.f) : r2;
            }
            __syncthreads();
        }
        if (ps < 3) { __threadfence(); grid.sync(); }
    }
}

// ---------------- fallback per-pass kernels (proven R10 forms) ----------------
template <int MODE>
__global__ __launch_bounds__(512) void cheb1_s(const unsigned int* __restrict__ colbinned,
                                               const int* __restrict__ colbase,
                                               const int* __restrict__ coltot,
                                               const int* __restrict__ o,
                                               const int* __restrict__ sflag,
                                               const float* __restrict__ dinv,
                                               const float* __restrict__ w_in,
                                               const float* __restrict__ wp2,
                                               float* __restrict__ w_out) {
    __shared__ float part[CNOD][4];
    __shared__ float accA[CNOD];
    int b = blockIdx.x, t = threadIdx.x;
    if (sflag[b]) {
        if (t < CNOD) accA[t] = 0.f;
        __syncthreads();
        int s0 = colbase[b], n = coltot[b];
        for (int i = t; i < n; i += 512) {
            unsigned int rec = colbinned[s0 + i];
            atomicAdd(&accA[rec & 127], w_in[rec >> 7]);
        }
        __syncthreads();
        if (t < CNOD) { part[t][0] = accA[t]; part[t][1] = 0.f; part[t][2] = 0.f; part[t][3] = 0.f; }
    } else {
        int nl = t >> 2, q = t & 3;
        int node = b * CNOD + nl;
        int os = o[node], oe = o[node + 1];
        float a = 0.f;
        for (int i = os + q; i < oe; i += 4)
            a += w_in[__builtin_nontemporal_load(&colbinned[i]) >> 7];
        part[nl][q] = a;
    }
    __syncthreads();
    if (t < CNOD) {
        float a = part[t][0] + part[t][1] + part[t][2] + part[t][3];
        int node = b * CNOD + t;
        float dn = dinv[node];
        float lh = (dn > 0.f) ? -dn * a : -w_in[node];
        float s = (dn > 0.f) ? dn : 1.f;
        w_out[node] = (MODE == 0) ? s * lh : s * (2.f * lh) - wp2[node];
    }
}

__global__ __launch_bounds__(256) void h1_kernel(const float* __restrict__ x,
        const float* __restrict__ wt1, const float* __restrict__ wt2,
        const float* __restrict__ wt3, const float* __restrict__ wt4,
        const float* __restrict__ dinv, const float* __restrict__ rinv,
        const float* __restrict__ W1, const float* __restrict__ b1,
        const float* __restrict__ W20, const float* __restrict__ b2,
        float* __restrict__ sh1, _Float16* __restrict__ s1t,
        float* __restrict__ accg) {
    int n = blockIdx.x * 256 + threadIdx.x;
    float rn = rinv[n], dn = dinv[n];
    float s = (dn > 0.f) ? dn : 1.f;
    float T0 = x[n], T1 = wt1[n] * rn, T2 = wt2[n] * rn, T3 = wt3[n] * rn, T4 = wt4[n] * rn;
    float h[HID];
    #pragma unroll
    for (int j = 0; j < HID; ++j) {
        float v = b1[j] + T0 * W1[j] + T1 * W1[8 + j] + T2 * W1[16 + j]
                + T3 * W1[24 + j] + T4 * W1[32 + j];
        h[j] = fmaxf(v, 0.f);
    }
    f4v sv0, sv1, av0, av1;
    h8v hv;
    #pragma unroll
    for (int j = 0; j < 4; ++j) { sv0[j] = s * h[j]; sv1[j] = s * h[4 + j]; }
    #pragma unroll
    for (int j = 0; j < 8; ++j) hv[j] = (_Float16)(s * h[j]);
    #pragma unroll
    for (int o2 = 0; o2 < HID; ++o2) {
        float v = b2[o2];
        #pragma unroll
        for (int j = 0; j < HID; ++j) v = fmaf(h[j], W20[j * 8 + o2], v);
        if (o2 < 4) av0[o2] = v; else av1[o2 - 4] = v;
    }
    *(f4v*)&sh1[n * 8] = sv0;  *(f4v*)&sh1[n * 8 + 4] = sv1;
    *(h8v*)&s1t[n * 8] = hv;
    *(f4v*)&accg[n * 8] = av0; *(f4v*)&accg[n * 8 + 4] = av1;
}

template <int MODE>
__global__ __launch_bounds__(512) void cheb8_e(const unsigned int* __restrict__ colbinned,
        const int* __restrict__ colbase, const int* __restrict__ coltot,
        const int* __restrict__ o, const int* __restrict__ sflag,
        const float* __restrict__ dinv, const float* __restrict__ rinv,
        const _Float16* __restrict__ w16_in, const float* __restrict__ w_in,
        const float* __restrict__ wp2,
        float* __restrict__ w_out, _Float16* __restrict__ w16_out,
        const float* __restrict__ Wk, float* __restrict__ accg) {
    __shared__ float pl[CNOD][4][9];
    __shared__ float vb[CNOD][HID];
    __shared__ float wk[64];
    __shared__ float accA[CNOD * 9];
    int b = blockIdx.x, t = threadIdx.x;
    if (t < 64) wk[t] = Wk[t];
    int nl = t >> 2, l = t & 3;
    int node = b * CNOD + nl;
    float a[8];
    #pragma unroll
    for (int j = 0; j < 8; ++j) a[j] = 0.f;
    if (!sflag[b]) {
        int os = o[node], oe = o[node + 1];
        for (int i = os + l; i < oe; i += 4) {
            unsigned int rec = __builtin_nontemporal_load(&colbinned[i]);
            h8v hv = *(const h8v*)&w16_in[(rec >> 7) * 8];
            #pragma unroll
            for (int j = 0; j < 8; ++j) a[j] += (float)hv[j];
        }
    } else {
        for (int i2 = t; i2 < CNOD * 9; i2 += 512) accA[i2] = 0.f;
        __syncthreads();
        int s0 = colbase[b], n = coltot[b];
        for (int i = t; i < n; i += 512) {
            unsigned int rec = colbinned[s0 + i];
            h8v hv = *(const h8v*)&w16_in[(rec >> 7) * 8];
            float* ap = &accA[(rec & 127) * 9];
            #pragma unroll
            for (int j = 0; j < 8; ++j) atomicAdd(ap + j, (float)hv[j]);
        }
        __syncthreads();
        if (l == 0) {
            #pragma unroll
            for (int j = 0; j < 8; ++j) a[j] = accA[nl * 9 + j];
        }
    }
    #pragma unroll
    for (int j = 0; j < 8; ++j) pl[nl][l][j] = a[j];
    __syncthreads();
    #pragma unroll
    for (int k2 = 0; k2 < 2; ++k2) {
        int idx = k2 * 512 + t;
        int n2 = idx >> 3, jj = idx & 7;
        int nd = b * CNOD + n2;
        float asum = pl[n2][0][jj] + pl[n2][1][jj] + pl[n2][2][jj] + pl[n2][3][jj];
        float dn = dinv[nd];
        float lh = (dn > 0.f) ? -dn * asum : -w_in[nd * 8 + jj];
        float T;
        if (MODE == 0) {
            T = lh;
            float w = (dn > 0.f) ? dn * lh : lh;
            w_out[nd * 8 + jj] = w;
            w16_out[nd * 8 + jj] = (_Float16)w;
        } else if (MODE == 1) {
            float sc = (dn > 0.f) ? dn : 1.f;
            float w = sc * (2.f * lh) - wp2[nd * 8 + jj];
            w_out[nd * 8 + jj] = w;
            w16_out[nd * 8 + jj] = (_Float16)w;
            T = w * rinv[nd];
        } else {
            T = 2.f * lh - wp2[nd * 8 + jj] * rinv[nd];
        }
        vb[n2][jj] = T;
    }
    __syncthreads();
    #pragma unroll
    for (int k2 = 0; k2 < 2; ++k2) {
        int idx = k2 * 512 + t;
        int n2 = idx >> 3, jj = idx & 7;
        int nd = b * CNOD + n2;
        float sum = 0.f;
        #pragma unroll
        for (int q = 0; q < HID; ++q) sum = fmaf(vb[n2][q], wk[q * 8 + jj], sum);
        float r2 = accg[nd * 8 + jj] + sum;
        accg[nd * 8 + jj] = (MODE == 2) ? fmaxf(r2, 0.f) : r2;
    }
}

// ---------------- dense layers ----------------
__global__ __launch_bounds__(256) void lin1_kernel(const float* __restrict__ h2,
                                                   const float* __restrict__ w,
                                                   float* __restrict__ part) {
    int chunk = blockIdx.x, t = threadIdx.x;
    int fbase = chunk * FC;
    __shared__ __align__(16) float a[FC * 20];
    for (int i = t; i < BSZ * FC; i += 256) {
        int bb = i >> 7, f = i & (FC - 1);
        a[f * 20 + bb] = h2[(size_t)bb * 65536 + fbase + f];
    }
    __syncthreads();
    f4v acc[16];
    #pragma unroll
    for (int bb = 0; bb < 16; ++bb) acc[bb] = (f4v)(0.f);
    int m = t * 4;
    if (m < MDIM) {
        for (int f = 0; f < FC; ++f) {
            f4v wv = __builtin_nontemporal_load((const f4v*)&w[(size_t)(fbase + f) * MDIM + m]);
            const f4v* ar = (const f4v*)&a[f * 20];
            f4v a0 = ar[0], a1 = ar[1], a2 = ar[2], a3 = ar[3];
            acc[0] += a0.x * wv;  acc[1] += a0.y * wv;  acc[2] += a0.z * wv;  acc[3] += a0.w * wv;
            acc[4] += a1.x * wv;  acc[5] += a1.y * wv;  acc[6] += a1.z * wv;  acc[7] += a1.w * wv;
            acc[8] += a2.x * wv;  acc[9] += a2.y * wv;  acc[10] += a2.z * wv; acc[11] += a2.w * wv;
            acc[12] += a3.x * wv; acc[13] += a3.y * wv; acc[14] += a3.z * wv; acc[15] += a3.w * wv;
        }
    }
    #pragma unroll
    for (int bb = 0; bb < 16; ++bb) {
        __builtin_nontemporal_store(acc[bb], (f4v*)&part[((size_t)chunk * 16 + bb) * 1024 + m]);
    }
}

__global__ __launch_bounds__(256) void hidden1(const float* __restrict__ part,
                                               float* __restrict__ part2) {
    int g = blockIdx.x >> 6;
    int off = (blockIdx.x & 63) * 256 + threadIdx.x;
    float s = 0.f;
    const float* p = part + (size_t)g * 64 * 16384 + off;
    for (int c = 0; c < 64; ++c) s += __builtin_nontemporal_load(&p[c * 16384]);
    part2[g * 16384 + off] = s;
}

__global__ __launch_bounds__(256) void hidden2(const float* __restrict__ part2,
                                               const float* __restrict__ lb,
                                               float* __restrict__ hid) {
    int off = blockIdx.x * 256 + threadIdx.x;
    int b = off >> 10, m = off & 1023;
    if (m >= MDIM) return;
    float s = lb[m];
    for (int g = 0; g < 8; ++g) s += part2[g * 16384 + off];
    hid[b * MDIM + m] = fmaxf(s, 0.f);
}

__global__ void out_kernel(const float* __restrict__ hid, const float* __restrict__ w2,
                           const float* __restrict__ b2, float* __restrict__ out) {
    int i = blockIdx.x * blockDim.x + threadIdx.x;
    if (i >= BSZ * ODIM) return;
    int b = i / ODIM, o = i % ODIM;
    float s = b2[o];
    for (int m = 0; m < MDIM; ++m) s = fmaf(hid[b * MDIM + m], w2[m * ODIM + o], s);
    out[i] = s;
}

extern "C" void kernel_launch(void* const* d_in, const int* in_sizes, int n_in,
                              void* d_out, int out_size, void* d_ws, size_t ws_size,
                              hipStream_t stream) {
    const float* x      = (const float*)d_in[0];
    const int*   ei     = (const int*)d_in[1];
    const float* W1     = (const float*)d_in[4];
    const float* b1     = (const float*)d_in[5];
    const float* W2     = (const float*)d_in[6];
    const float* b2     = (const float*)d_in[7];
    const float* lin1w  = (const float*)d_in[8];
    const float* lin1b  = (const float*)d_in[9];
    const float* lin2w  = (const float*)d_in[10];
    const float* lin2b  = (const float*)d_in[11];
    float* out = (float*)d_out;

    // ---- workspace layout (~75 MB of d_ws) ----
    unsigned int* colbinned = (unsigned int*)d_ws;               // NE (16 MB)
    _Float16* s1t = (_Float16*)(colbinned + NE);                 // 2 MB
    _Float16* s2t = s1t + 8 * (size_t)NN;                        // 2 MB
    unsigned char* rowbinned = (unsigned char*)(s2t + 8 * (size_t)NN); // 4 MB
    float* wA   = (float*)(rowbinned + NE);                      // 8*NN
    float* wB   = wA + 8 * (size_t)NN;                           // 8*NN
    float* sh1  = wB + 8 * (size_t)NN;                           // 8*NN
    float* wt1  = sh1 + 8 * (size_t)NN;                          // NN each
    float* wt2  = wt1 + NN;
    float* wt3  = wt2 + NN;
    float* wt4  = wt3 + NN;
    float* sx   = wt4 + NN;
    float* dinv = sx + NN;
    float* rinv = dinv + NN;
    int* colhist = (int*)(rinv + NN);                            // NB*NBUK (4 MB)
    int* rowhist = colhist + (size_t)NB * NBUK;                  // NB*NBUKR (2 MB)
    int* coltot  = rowhist + (size_t)NB * NBUKR;                 // NBUK
    int* colbase = coltot + NBUK;                                // NBUK
    int* rowtot  = colbase + NBUK;                               // NBUKR
    int* rowbase = rowtot + NBUKR;                               // NBUKR
    int* o       = rowbase + NBUKR;                              // NN+1
    int* sflag   = o + NN + 1;                                   // NBUK
    float* accg  = (float*)(sflag + NBUK);                       // 8*NN
    float* hid   = accg + 8 * (size_t)NN;                        // BSZ*1024
    float* part2 = hid + BSZ * 1024;                             // 8*16384
    float* part  = part2 + 8 * 16384;                            // 32 MB

    // build
    bin_count<<<NB, 512, 0, stream>>>(ei, colhist, rowhist);
    bin_scan<<<NBUK, NB, 0, stream>>>(colhist, coltot, NBUK);
    bin_scan<<<NBUKR, NB, 0, stream>>>(rowhist, rowtot, NBUKR);
    base_scan<4><<<1, 256, 0, stream>>>(coltot, colbase);
    base_scan<2><<<1, 256, 0, stream>>>(rowtot, rowbase);
    bin_fill<<<NB, 512, 0, stream>>>(ei, colhist, rowhist, colbase, rowbase, colbinned, rowbinned);
    bucket_sort2<<<NBUK, 256, 0, stream>>>(colbinned, colbase, coltot, o, sflag);
    deg_finish<<<NBUKR, 256, 0, stream>>>(rowbinned, rowbase, rowtot, x, dinv, rinv, sx);

    // graph phase: cooperative mega-kernel; deterministic fallback to per-pass kernels
    MegaP mp;
    mp.colbinned = colbinned; mp.colbase = colbase; mp.coltot = coltot;
    mp.o = o; mp.sflag = sflag;
    mp.dinv = dinv; mp.rinv = rinv; mp.x = x; mp.sx = sx;
    mp.wt1 = wt1; mp.wt2 = wt2; mp.wt3 = wt3; mp.wt4 = wt4;
    mp.W1 = W1; mp.b1 = b1; mp.W2 = W2; mp.b2 = b2;
    mp.sh1 = sh1; mp.s1t = s1t; mp.s2t = s2t;
    mp.wA = wA; mp.wB = wB; mp.accg = accg;
    void* kargs[] = { &mp };
    hipError_t cerr = hipLaunchCooperativeKernel((const void*)cheb_mega,
                                                 dim3(MGRID), dim3(512), kargs, 0, stream);
    if (cerr != hipSuccess) {
        cheb1_s<0><<<NBUK, 512, 0, stream>>>(colbinned, colbase, coltot, o, sflag, dinv, sx, nullptr, wt1);
        cheb1_s<1><<<NBUK, 512, 0, stream>>>(colbinned, colbase, coltot, o, sflag, dinv, wt1, sx, wt2);
        cheb1_s<1><<<NBUK, 512, 0, stream>>>(colbinned, colbase, coltot, o, sflag, dinv, wt2, wt1, wt3);
        cheb1_s<1><<<NBUK, 512, 0, stream>>>(colbinned, colbase, coltot, o, sflag, dinv, wt3, wt2, wt4);
        h1_kernel<<<NN / 256, 256, 0, stream>>>(x, wt1, wt2, wt3, wt4, dinv, rinv,
                                                W1, b1, W2, b2, sh1, s1t, accg);
        cheb8_e<0><<<NBUK, 512, 0, stream>>>(colbinned, colbase, coltot, o, sflag, dinv, rinv,
                                             s1t, sh1, nullptr, wA, s2t, W2 + 64, accg);
        cheb8_e<1><<<NBUK, 512, 0, stream>>>(colbinned, colbase, coltot, o, sflag, dinv, rinv,
                                             s2t, wA, sh1, wB, s1t, W2 + 128, accg);
        cheb8_e<1><<<NBUK, 512, 0, stream>>>(colbinned, colbase, coltot, o, sflag, dinv, rinv,
                                             s1t, wB, wA, wA, s2t, W2 + 192, accg);
        cheb8_e<2><<<NBUK, 512, 0, stream>>>(colbinned, colbase, coltot, o, sflag, dinv, rinv,
                                             s2t, wA, wB, nullptr, nullptr, W2 + 256, accg);
    }
    // accg now holds h2

    // dense
    lin1_kernel<<<NCHUNK, 256, 0, stream>>>(accg, lin1w, part);
    hidden1<<<512, 256, 0, stream>>>(part, part2);
    hidden2<<<64, 256, 0, stream>>>(part2, lin1b, hid);
    out_kernel<<<3, 256, 0, stream>>>(hid, lin2w, lin2b, out);
}

// Round 14
// 599.276 us; speedup vs baseline: 3.1269x; 3.1269x over previous
//
#include <hip/hip_runtime.h>

#define NN 131072          // nodes (2^17)
#define NE 4194304         // edges
#define HID 8
#define BSZ 16
#define MDIM 1000
#define ODIM 34
#define FC 128             // f-chunk per lin1 block
#define NCHUNK 512         // 65536 / FC
#define NB 256             // edge stripes for binning (64B colbinned runs)
#define EPB (NE / NB)      // 16384
#define NBUK 1024          // dst buckets (128 nodes each)
#define CNOD 128
#define NBUKR 512          // row buckets (256 nodes each)
#define SCAP 6144          // bucket sort LDS capacity (mean 4096, sd 64)

typedef float f4v __attribute__((ext_vector_type(4)));
typedef _Float16 h8v __attribute__((ext_vector_type(8)));

// ---------------- binning build (no global atomics) ----------------
__global__ __launch_bounds__(512) void bin_count(const int* __restrict__ ei,
                                                 int* __restrict__ colhist,
                                                 int* __restrict__ rowhist) {
    __shared__ int ch[NBUK];
    __shared__ int rh[NBUKR];
    int b = blockIdx.x, t = threadIdx.x;
    for (int i = t; i < NBUK; i += 512) ch[i] = 0;
    for (int i = t; i < NBUKR; i += 512) rh[i] = 0;
    __syncthreads();
    int base = b * EPB;
    for (int k = t; k < EPB; k += 512) {
        int e = base + k;
        int r = __builtin_nontemporal_load(&ei[e]);
        int c = __builtin_nontemporal_load(&ei[NE + e]);
        if (r != c) { atomicAdd(&ch[c >> 7], 1); atomicAdd(&rh[r >> 8], 1); }
    }
    __syncthreads();
    for (int i = t; i < NBUK; i += 512) colhist[b * NBUK + i] = ch[i];
    for (int i = t; i < NBUKR; i += 512) rowhist[b * NBUKR + i] = rh[i];
}

// per-bucket scan across NB stripes; hist[stripe][bucket] -> local exclusive offsets
__global__ __launch_bounds__(NB) void bin_scan(int* __restrict__ hist,
                                               int* __restrict__ tot, int nbuckets) {
    __shared__ int s[NB];
    int i = blockIdx.x, t = threadIdx.x;
    int v = hist[(size_t)t * nbuckets + i];
    s[t] = v; __syncthreads();
    for (int off = 1; off < NB; off <<= 1) {
        int x = (t >= off) ? s[t - off] : 0;
        __syncthreads(); s[t] += x; __syncthreads();
    }
    hist[(size_t)t * nbuckets + i] = s[t] - v;
    if (t == NB - 1) tot[i] = s[t];
}

template <int M>
__global__ __launch_bounds__(256) void base_scan(const int* __restrict__ tot,
                                                 int* __restrict__ basev) {
    __shared__ int s[256];
    int t = threadIdx.x;
    int v[M]; int ps = 0;
    #pragma unroll
    for (int q = 0; q < M; ++q) { v[q] = tot[t * M + q]; ps += v[q]; }
    s[t] = ps; __syncthreads();
    for (int off = 1; off < 256; off <<= 1) {
        int x = (t >= off) ? s[t - off] : 0;
        __syncthreads(); s[t] += x; __syncthreads();
    }
    int run = s[t] - ps;
    #pragma unroll
    for (int q = 0; q < M; ++q) { basev[t * M + q] = run; run += v[q]; }
}

__global__ __launch_bounds__(512) void bin_fill(const int* __restrict__ ei,
                                                const int* __restrict__ colhist,
                                                const int* __restrict__ rowhist,
                                                const int* __restrict__ colbase,
                                                const int* __restrict__ rowbase,
                                                unsigned int* __restrict__ colbinned,
                                                unsigned char* __restrict__ rowbinned) {
    __shared__ int cc[NBUK];
    __shared__ int rc[NBUKR];
    int b = blockIdx.x, t = threadIdx.x;
    for (int i = t; i < NBUK; i += 512) cc[i] = colbase[i] + colhist[b * NBUK + i];
    for (int i = t; i < NBUKR; i += 512) rc[i] = rowbase[i] + rowhist[b * NBUKR + i];
    __syncthreads();
    int base = b * EPB;
    for (int k = t; k < EPB; k += 512) {
        int e = base + k;
        int r = __builtin_nontemporal_load(&ei[e]);
        int c = __builtin_nontemporal_load(&ei[NE + e]);
        if (r != c) {
            int p = atomicAdd(&cc[c >> 7], 1);
            colbinned[p] = ((unsigned)r << 7) | (unsigned)(c & 127);
            int q = atomicAdd(&rc[r >> 8], 1);
            rowbinned[q] = (unsigned char)(r & 255);
        }
    }
}

// per-bucket counting sort by dst node (cl) + per-node CSR offsets o[].
// Oversized bucket (P~0): left unsorted, sflag=1, runs empty -> atomic fallback in cheb.
__global__ __launch_bounds__(256) void bucket_sort2(unsigned int* __restrict__ colbinned,
                                                    const int* __restrict__ colbase,
                                                    const int* __restrict__ coltot,
                                                    int* __restrict__ o,
                                                    int* __restrict__ sflag) {
    __shared__ unsigned int recs[SCAP];
    __shared__ int cnt[CNOD], scn[CNOD], cur[CNOD];
    int b = blockIdx.x, t = threadIdx.x;
    int s0 = colbase[b], n = coltot[b];
    if (n > SCAP) {
        if (t == 0) sflag[b] = 1;
        for (int i = t; i < CNOD; i += 256) o[b * CNOD + i] = s0;
        if (b == NBUK - 1 && t == 0) o[NN] = s0 + n;
        return;
    }
    if (t == 0) sflag[b] = 0;
    for (int i = t; i < CNOD; i += 256) cnt[i] = 0;
    __syncthreads();
    for (int i = t; i < n; i += 256) {
        unsigned int rec = colbinned[s0 + i];
        recs[i] = rec;
        atomicAdd(&cnt[rec & 127], 1);
    }
    __syncthreads();
    if (t < CNOD) scn[t] = cnt[t];
    __syncthreads();
    for (int off = 1; off < CNOD; off <<= 1) {
        int v = 0;
        if (t < CNOD && t >= off) v = scn[t - off];
        __syncthreads();
        if (t < CNOD) scn[t] += v;
        __syncthreads();
    }
    if (t < CNOD) {
        int ex = scn[t] - cnt[t];
        cur[t] = ex;
        o[b * CNOD + t] = s0 + ex;
    }
    __syncthreads();
    if (b == NBUK - 1 && t == 0) o[NN] = s0 + n;
    for (int i = t; i < n; i += 256) {
        unsigned int rec = recs[i];
        int p = atomicAdd(&cur[rec & 127], 1);
        colbinned[s0 + p] = rec;
    }
}

// degree histogram per row bucket -> dinv, rinv, sx (scaled x)
__global__ __launch_bounds__(256) void deg_finish(const unsigned char* __restrict__ rowbinned,
                                                  const int* __restrict__ rowbase,
                                                  const int* __restrict__ rowtot,
                                                  const float* __restrict__ x,
                                                  float* __restrict__ dinv,
                                                  float* __restrict__ rinv,
                                                  float* __restrict__ sx) {
    __shared__ int cnt[256];
    int b = blockIdx.x, t = threadIdx.x;
    cnt[t] = 0; __syncthreads();
    int s0 = rowbase[b], n = rowtot[b];
    for (int i = t; i < n; i += 256) atomicAdd(&cnt[rowbinned[s0 + i]], 1);
    __syncthreads();
    int d = cnt[t];
    int node = b * 256 + t;
    float dn = (d > 0) ? rsqrtf((float)d) : 0.f;
    dinv[node] = dn;
    rinv[node] = (d > 0) ? sqrtf((float)d) : 1.f;
    sx[node] = ((d > 0) ? dn : 1.f) * x[node];
}

// ---------------- layer 1 (scalar): stride-4 interleaved runs, register accumulation ----------------
template <int MODE>   // 0: first (T1), 1: recurrence
__global__ __launch_bounds__(512) void cheb1_s(const unsigned int* __restrict__ colbinned,
                                               const int* __restrict__ colbase,
                                               const int* __restrict__ coltot,
                                               const int* __restrict__ o,
                                               const int* __restrict__ sflag,
                                               const float* __restrict__ dinv,
                                               const float* __restrict__ w_in,
                                               const float* __restrict__ wp2,
                                               float* __restrict__ w_out) {
    __shared__ float part[CNOD][4];
    __shared__ float accA[CNOD];
    int b = blockIdx.x, t = threadIdx.x;
    if (sflag[b]) {                       // rare fallback: atomic path
        if (t < CNOD) accA[t] = 0.f;
        __syncthreads();
        int s0 = colbase[b], n = coltot[b];
        for (int i = t; i < n; i += 512) {
            unsigned int rec = colbinned[s0 + i];
            atomicAdd(&accA[rec & 127], w_in[rec >> 7]);
        }
        __syncthreads();
        if (t < CNOD) { part[t][0] = accA[t]; part[t][1] = 0.f; part[t][2] = 0.f; part[t][3] = 0.f; }
    } else {                              // 4 lanes/node, stride-4 interleave (coalesced recs)
        int nl = t >> 2, q = t & 3;
        int node = b * CNOD + nl;
        int os = o[node], oe = o[node + 1];
        float a = 0.f;
        for (int i = os + q; i < oe; i += 4) {
            unsigned int rec = __builtin_nontemporal_load(&colbinned[i]);
            a += w_in[rec >> 7];
        }
        part[nl][q] = a;
    }
    __syncthreads();
    if (t < CNOD) {
        float a = part[t][0] + part[t][1] + part[t][2] + part[t][3];
        int node = b * CNOD + t;
        float dn = dinv[node];
        float lh = (dn > 0.f) ? -dn * a : -w_in[node];
        float s = (dn > 0.f) ? dn : 1.f;
        w_out[node] = (MODE == 0) ? s * lh : s * (2.f * lh) - wp2[node];
    }
}

// h1 = relu(sum Tk W1[k]) ; writes sh1 (fp32), s1t (fp16 table), accg = b2 + h1@W2[0]
__global__ __launch_bounds__(256) void h1_kernel(const float* __restrict__ x,
        const float* __restrict__ wt1, const float* __restrict__ wt2,
        const float* __restrict__ wt3, const float* __restrict__ wt4,
        const float* __restrict__ dinv, const float* __restrict__ rinv,
        const float* __restrict__ W1, const float* __restrict__ b1,
        const float* __restrict__ W20, const float* __restrict__ b2,
        float* __restrict__ sh1, _Float16* __restrict__ s1t,
        float* __restrict__ accg) {
    int n = blockIdx.x * 256 + threadIdx.x;
    float rn = rinv[n], dn = dinv[n];
    float s = (dn > 0.f) ? dn : 1.f;
    float T0 = x[n], T1 = wt1[n] * rn, T2 = wt2[n] * rn, T3 = wt3[n] * rn, T4 = wt4[n] * rn;
    float h[HID];
    #pragma unroll
    for (int j = 0; j < HID; ++j) {
        float v = b1[j] + T0 * W1[j] + T1 * W1[8 + j] + T2 * W1[16 + j]
                + T3 * W1[24 + j] + T4 * W1[32 + j];
        h[j] = fmaxf(v, 0.f);
    }
    f4v sv0, sv1, av0, av1;
    h8v hv;
    #pragma unroll
    for (int j = 0; j < 4; ++j) { sv0[j] = s * h[j]; sv1[j] = s * h[4 + j]; }
    #pragma unroll
    for (int j = 0; j < 8; ++j) hv[j] = (_Float16)(s * h[j]);
    #pragma unroll
    for (int o2 = 0; o2 < HID; ++o2) {
        float v = b2[o2];
        #pragma unroll
        for (int j = 0; j < HID; ++j) v = fmaf(h[j], W20[j * 8 + o2], v);
        if (o2 < 4) av0[o2] = v; else av1[o2 - 4] = v;
    }
    *(f4v*)&sh1[n * 8] = sv0;  *(f4v*)&sh1[n * 8 + 4] = sv1;
    *(h8v*)&s1t[n * 8] = hv;
    *(f4v*)&accg[n * 8] = av0; *(f4v*)&accg[n * 8 + 4] = av1;
}

// ---------------- layer 2: edge-parallel lanes, full-feature register accumulation ----------------
template <int MODE>   // 0 first, 1 mid, 2 final (relu, no w_out)
__global__ __launch_bounds__(512) void cheb8_e(const unsigned int* __restrict__ colbinned,
        const int* __restrict__ colbase, const int* __restrict__ coltot,
        const int* __restrict__ o, const int* __restrict__ sflag,
        const float* __restrict__ dinv, const float* __restrict__ rinv,
        const _Float16* __restrict__ w16_in, const float* __restrict__ w_in,
        const float* __restrict__ wp2,
        float* __restrict__ w_out, _Float16* __restrict__ w16_out,
        const float* __restrict__ Wk, float* __restrict__ accg) {
    __shared__ float pl[CNOD][4][9];      // per-(node,lane) partials, pad 9
    __shared__ float vb[CNOD][HID];
    __shared__ float wk[64];
    __shared__ float accA[CNOD * 9];      // atomic fallback only
    int b = blockIdx.x, t = threadIdx.x;
    if (t < 64) wk[t] = Wk[t];
    int nl = t >> 2, l = t & 3;
    int node = b * CNOD + nl;
    float a[8];
    #pragma unroll
    for (int j = 0; j < 8; ++j) a[j] = 0.f;
    if (!sflag[b]) {
        // lane l walks edges os+l, os+l+4, ... : 4 lanes' rec loads are 16B-contiguous
        int os = o[node], oe = o[node + 1];
        for (int i = os + l; i < oe; i += 4) {
            unsigned int rec = __builtin_nontemporal_load(&colbinned[i]);
            h8v hv = *(const h8v*)&w16_in[(rec >> 7) * 8];
            #pragma unroll
            for (int j = 0; j < 8; ++j) a[j] += (float)hv[j];
        }
    } else {                              // rare fallback: atomic path
        for (int i2 = t; i2 < CNOD * 9; i2 += 512) accA[i2] = 0.f;
        __syncthreads();
        int s0 = colbase[b], n = coltot[b];
        for (int i = t; i < n; i += 512) {
            unsigned int rec = colbinned[s0 + i];
            int r = rec >> 7, cl = rec & 127;
            h8v hv = *(const h8v*)&w16_in[r * 8];
            float* ap = &accA[cl * 9];
            #pragma unroll
            for (int j = 0; j < 8; ++j) atomicAdd(ap + j, (float)hv[j]);
        }
        __syncthreads();
        if (l == 0) {
            #pragma unroll
            for (int j = 0; j < 8; ++j) a[j] = accA[nl * 9 + j];
        }
    }
    #pragma unroll
    for (int j = 0; j < 8; ++j) pl[nl][l][j] = a[j];
    __syncthreads();
    // combine: 512 threads x 2 -> (node, feature)
    #pragma unroll
    for (int k2 = 0; k2 < 2; ++k2) {
        int idx = k2 * 512 + t;
        int n2 = idx >> 3, jj = idx & 7;
        int nd = b * CNOD + n2;
        float asum = pl[n2][0][jj] + pl[n2][1][jj] + pl[n2][2][jj] + pl[n2][3][jj];
        float dn = dinv[nd];
        float lh = (dn > 0.f) ? -dn * asum : -w_in[nd * 8 + jj];
        float T;
        if (MODE == 0) {
            T = lh;
            float w = (dn > 0.f) ? dn * lh : lh;
            w_out[nd * 8 + jj] = w;
            w16_out[nd * 8 + jj] = (_Float16)w;
        } else if (MODE == 1) {
            float sc = (dn > 0.f) ? dn : 1.f;
            float w = sc * (2.f * lh) - wp2[nd * 8 + jj];
            w_out[nd * 8 + jj] = w;
            w16_out[nd * 8 + jj] = (_Float16)w;
            T = w * rinv[nd];
        } else {
            T = 2.f * lh - wp2[nd * 8 + jj] * rinv[nd];
        }
        vb[n2][jj] = T;
    }
    __syncthreads();
    #pragma unroll
    for (int k2 = 0; k2 < 2; ++k2) {
        int idx = k2 * 512 + t;
        int n2 = idx >> 3, jj = idx & 7;
        int nd = b * CNOD + n2;
        float sum = 0.f;
        #pragma unroll
        for (int q = 0; q < HID; ++q) sum = fmaf(vb[n2][q], wk[q * 8 + jj], sum);
        float r2 = accg[nd * 8 + jj] + sum;
        accg[nd * 8 + jj] = (MODE == 2) ? fmaxf(r2, 0.f) : r2;
    }
}

// ---------------- dense layers ----------------
__global__ __launch_bounds__(256) void lin1_kernel(const float* __restrict__ h2,
                                                   const float* __restrict__ w,
                                                   float* __restrict__ part) {
    int chunk = blockIdx.x, t = threadIdx.x;
    int fbase = chunk * FC;
    __shared__ __align__(16) float a[FC * 20];
    for (int i = t; i < BSZ * FC; i += 256) {
        int bb = i >> 7, f = i & (FC - 1);
        a[f * 20 + bb] = h2[(size_t)bb * 65536 + fbase + f];
    }
    __syncthreads();
    f4v acc[16];
    #pragma unroll
    for (int bb = 0; bb < 16; ++bb) acc[bb] = (f4v)(0.f);
    int m = t * 4;
    if (m < MDIM) {
        for (int f = 0; f < FC; ++f) {
            f4v wv = __builtin_nontemporal_load((const f4v*)&w[(size_t)(fbase + f) * MDIM + m]);
            const f4v* ar = (const f4v*)&a[f * 20];
            f4v a0 = ar[0], a1 = ar[1], a2 = ar[2], a3 = ar[3];
            acc[0] += a0.x * wv;  acc[1] += a0.y * wv;  acc[2] += a0.z * wv;  acc[3] += a0.w * wv;
            acc[4] += a1.x * wv;  acc[5] += a1.y * wv;  acc[6] += a1.z * wv;  acc[7] += a1.w * wv;
            acc[8] += a2.x * wv;  acc[9] += a2.y * wv;  acc[10] += a2.z * wv; acc[11] += a2.w * wv;
            acc[12] += a3.x * wv; acc[13] += a3.y * wv; acc[14] += a3.z * wv; acc[15] += a3.w * wv;
        }
    }
    #pragma unroll
    for (int bb = 0; bb < 16; ++bb) {
        __builtin_nontemporal_store(acc[bb], (f4v*)&part[((size_t)chunk * 16 + bb) * 1024 + m]);
    }
}

__global__ __launch_bounds__(256) void hidden1(const float* __restrict__ part,
                                               float* __restrict__ part2) {
    int g = blockIdx.x >> 6;
    int off = (blockIdx.x & 63) * 256 + threadIdx.x;
    float s = 0.f;
    const float* p = part + (size_t)g * 64 * 16384 + off;
    for (int c = 0; c < 64; ++c) s += __builtin_nontemporal_load(&p[c * 16384]);
    part2[g * 16384 + off] = s;
}

__global__ __launch_bounds__(256) void hidden2(const float* __restrict__ part2,
                                               const float* __restrict__ lb,
                                               float* __restrict__ hid) {
    int off = blockIdx.x * 256 + threadIdx.x;
    int b = off >> 10, m = off & 1023;
    if (m >= MDIM) return;
    float s = lb[m];
    for (int g = 0; g < 8; ++g) s += part2[g * 16384 + off];
    hid[b * MDIM + m] = fmaxf(s, 0.f);
}

__global__ void out_kernel(const float* __restrict__ hid, const float* __restrict__ w2,
                           const float* __restrict__ b2, float* __restrict__ out) {
    int i = blockIdx.x * blockDim.x + threadIdx.x;
    if (i >= BSZ * ODIM) return;
    int b = i / ODIM, o = i % ODIM;
    float s = b2[o];
    for (int m = 0; m < MDIM; ++m) s = fmaf(hid[b * MDIM + m], w2[m * ODIM + o], s);
    out[i] = s;
}

extern "C" void kernel_launch(void* const* d_in, const int* in_sizes, int n_in,
                              void* d_out, int out_size, void* d_ws, size_t ws_size,
                              hipStream_t stream) {
    const float* x      = (const float*)d_in[0];
    const int*   ei     = (const int*)d_in[1];
    const float* W1     = (const float*)d_in[4];
    const float* b1     = (const float*)d_in[5];
    const float* W2     = (const float*)d_in[6];
    const float* b2     = (const float*)d_in[7];
    const float* lin1w  = (const float*)d_in[8];
    const float* lin1b  = (const float*)d_in[9];
    const float* lin2w  = (const float*)d_in[10];
    const float* lin2b  = (const float*)d_in[11];
    float* out = (float*)d_out;

    // ---- workspace layout (~70 MB of d_ws) ----
    unsigned int* colbinned = (unsigned int*)d_ws;               // NE (16 MB)
    _Float16* s1t = (_Float16*)(colbinned + NE);                 // 2 MB
    _Float16* s2t = s1t + 8 * (size_t)NN;                        // 2 MB
    unsigned char* rowbinned = (unsigned char*)(s2t + 8 * (size_t)NN); // NE bytes (4 MB)
    float* wA   = (float*)(rowbinned + NE);                      // 8*NN
    float* wB   = wA + 8 * (size_t)NN;                           // 8*NN
    float* sh1  = wB + 8 * (size_t)NN;                           // 8*NN
    float* wt1  = sh1 + 8 * (size_t)NN;                          // NN each
    float* wt2  = wt1 + NN;
    float* wt3  = wt2 + NN;
    float* wt4  = wt3 + NN;
    float* sx   = wt4 + NN;
    float* dinv = sx + NN;
    float* rinv = dinv + NN;
    int* colhist = (int*)(rinv + NN);                            // NB*NBUK (1 MB)
    int* rowhist = colhist + (size_t)NB * NBUK;                  // NB*NBUKR (0.5 MB)
    int* coltot  = rowhist + (size_t)NB * NBUKR;                 // NBUK
    int* colbase = coltot + NBUK;                                // NBUK
    int* rowtot  = colbase + NBUK;                               // NBUKR
    int* rowbase = rowtot + NBUKR;                               // NBUKR
    int* o       = rowbase + NBUKR;                              // NN+1
    int* sflag   = o + NN + 1;                                   // NBUK
    float* accg  = (float*)(sflag + NBUK);                       // 8*NN
    float* hid   = accg + 8 * (size_t)NN;                        // BSZ*1024
    float* part2 = hid + BSZ * 1024;                             // 8*16384
    float* part  = part2 + 8 * 16384;                            // NCHUNK*16*1024 (32 MB)

    // build
    bin_count<<<NB, 512, 0, stream>>>(ei, colhist, rowhist);
    bin_scan<<<NBUK, NB, 0, stream>>>(colhist, coltot, NBUK);
    bin_scan<<<NBUKR, NB, 0, stream>>>(rowhist, rowtot, NBUKR);
    base_scan<4><<<1, 256, 0, stream>>>(coltot, colbase);
    base_scan<2><<<1, 256, 0, stream>>>(rowtot, rowbase);
    bin_fill<<<NB, 512, 0, stream>>>(ei, colhist, rowhist, colbase, rowbase, colbinned, rowbinned);
    bucket_sort2<<<NBUK, 256, 0, stream>>>(colbinned, colbase, coltot, o, sflag);
    deg_finish<<<NBUKR, 256, 0, stream>>>(rowbinned, rowbase, rowtot, x, dinv, rinv, sx);

    // layer 1 (scalar, fp32, atomic-free interleaved runs)
    cheb1_s<0><<<NBUK, 512, 0, stream>>>(colbinned, colbase, coltot, o, sflag, dinv, sx, nullptr, wt1);
    cheb1_s<1><<<NBUK, 512, 0, stream>>>(colbinned, colbase, coltot, o, sflag, dinv, wt1, sx, wt2);
    cheb1_s<1><<<NBUK, 512, 0, stream>>>(colbinned, colbase, coltot, o, sflag, dinv, wt2, wt1, wt3);
    cheb1_s<1><<<NBUK, 512, 0, stream>>>(colbinned, colbase, coltot, o, sflag, dinv, wt3, wt2, wt4);
    h1_kernel<<<NN / 256, 256, 0, stream>>>(x, wt1, wt2, wt3, wt4, dinv, rinv,
                                            W1, b1, W2, b2, sh1, s1t, accg);

    // layer 2 (fp16 gather tables, edge-parallel register accumulation, fused W2[k])
    cheb8_e<0><<<NBUK, 512, 0, stream>>>(colbinned, colbase, coltot, o, sflag, dinv, rinv,
                                         s1t, sh1, nullptr, wA, s2t, W2 + 64, accg);
    cheb8_e<1><<<NBUK, 512, 0, stream>>>(colbinned, colbase, coltot, o, sflag, dinv, rinv,
                                         s2t, wA, sh1, wB, s1t, W2 + 128, accg);
    cheb8_e<1><<<NBUK, 512, 0, stream>>>(colbinned, colbase, coltot, o, sflag, dinv, rinv,
                                         s1t, wB, wA, wA, s2t, W2 + 192, accg);
    cheb8_e<2><<<NBUK, 512, 0, stream>>>(colbinned, colbase, coltot, o, sflag, dinv, rinv,
                                         s2t, wA, wB, nullptr, nullptr, W2 + 256, accg);
    // accg now holds h2

    // dense
    lin1_kernel<<<NCHUNK, 256, 0, stream>>>(accg, lin1w, part);
    hidden1<<<512, 256, 0, stream>>>(part, part2);
    hidden2<<<64, 256, 0, stream>>>(part2, lin1b, hid);
    out_kernel<<<3, 256, 0, stream>>>(hid, lin2w, lin2b, out);
}